// Round 2
// baseline (688.656 us; speedup 1.0000x reference)
//
#include <hip/hip_runtime.h>
#include <hip/hip_bf16.h>

// StreamingSSMCell: B=8192, D=1024, DCONV=4.
// Diagnostic round: runtime dtype sniff (fp32 vs bf16 storage), dual-path
// global reads/writes, manual LDS staging (no global_load_lds).
// out layout (flat elements): out[8.39M] | h_new[8.39M] | new_buf[33.6M]

typedef float  floatx4 __attribute__((ext_vector_type(4)));
typedef __bf16 bf16x8  __attribute__((ext_vector_type(8)));
typedef unsigned short u16;
typedef unsigned short u16x8 __attribute__((ext_vector_type(8)));

__device__ __forceinline__ float bf2f(u16 u) {
    union { unsigned int i; float f; } v; v.i = ((unsigned int)u) << 16; return v.f;
}
__device__ __forceinline__ u16 f2bf(float f) {
    union { float ff; unsigned int i; } v; v.ff = f;
    return (u16)((v.i + 0x7fffu + ((v.i >> 16) & 1u)) >> 16);
}
__device__ __forceinline__ float silu_f(float x) { return x / (1.f + __expf(-x)); }

#define D_SZ 1024
#define ELEMS_OUT  8388608        // 8192*1024
#define ELEMS_HNEW 8388608
// element bases within d_out: out=0, h_new=8388608, new_buf=16777216

// ---------------------------------------------------------------------------
// dtype sniff: bf16 N(0,1) data has every u16 exponent-field in [64,160];
// fp32 data has random exponent fields at even u16 indices. flag=1 => fp32.
// ---------------------------------------------------------------------------
__global__ void k_sniff(const u16* __restrict__ x, int* __restrict__ flag) {
    if (threadIdx.x == 0 && blockIdx.x == 0) {
        int bad = 0;
        for (int i = 0; i < 64; ++i) {
            u16 u = x[2 * i];
            int e = (u >> 7) & 0xFF;
            if (e < 64 || e > 160) bad = 1;
        }
        *flag = bad;
    }
}

// ---------------------------------------------------------------------------
// Kernel 1: xz = x @ W_in^T + b_in (M=8192, K=1024) with fused conv/decay/
// gate epilogue. 128 batch rows x 64 d-columns per block; B-tile interleaves
// x-half and z-half rows of W_in so acc[i][j] (x) pairs acc[i][j+2] (z) in
// the same lane. g = h_new*silu(z) stored bf16 to ws.
// ---------------------------------------------------------------------------
__global__ __launch_bounds__(256)
void k1_inproj_fused(const void* __restrict__ xv, const void* __restrict__ hv_,
                     const void* __restrict__ cbv,
                     const void* __restrict__ wiv, const void* __restrict__ biv,
                     const void* __restrict__ cwv, const void* __restrict__ cbsv,
                     void* __restrict__ outv, u16* __restrict__ g_out,
                     const int* __restrict__ flagp)
{
    __shared__ u16 lA[128 * 64];
    __shared__ u16 lB[128 * 64];

    const int isf32 = *flagp;

    const u16*   xb = (const u16*)xv;     const float*  xf = (const float*)xv;
    const u16*   wb = (const u16*)wiv;    const float*  wf = (const float*)wiv;

    const int tid  = threadIdx.x;
    const int lane = tid & 63;
    const int wv   = tid >> 6;
    const int wave_m = wv >> 1, wave_n = wv & 1;
    const int m0 = blockIdx.x * 128;   // batch tile
    const int n0 = blockIdx.y * 64;    // d tile

    floatx4 acc[4][4];
#pragma unroll
    for (int i = 0; i < 4; ++i)
#pragma unroll
        for (int j = 0; j < 4; ++j) acc[i][j] = (floatx4){0.f, 0.f, 0.f, 0.f};

    for (int kt = 0; kt < 16; ++kt) {
        const int kbase = kt * 64;
#pragma unroll
        for (int c = 0; c < 4; ++c) {
            const int eoff = wv * 2048 + c * 512 + lane * 8; // elem offset in tile
            const int row  = eoff >> 6;        // 0..127
            const int cole = eoff & 63;        // multiple of 8
            const size_t gea = (size_t)(m0 + row) * D_SZ + kbase + cole;
            const int grow = n0 + ((row >> 6) & 1) * 32 + (row & 31) + ((row >> 5) & 1) * 1024;
            const size_t geb = (size_t)grow * D_SZ + kbase + cole;
            if (isf32) {
                floatx4 a0 = *(const floatx4*)(xf + gea);
                floatx4 a1 = *(const floatx4*)(xf + gea + 4);
                u16x8 ta = { f2bf(a0.x), f2bf(a0.y), f2bf(a0.z), f2bf(a0.w),
                             f2bf(a1.x), f2bf(a1.y), f2bf(a1.z), f2bf(a1.w) };
                *(u16x8*)&lA[eoff] = ta;
                floatx4 b0 = *(const floatx4*)(wf + geb);
                floatx4 b1 = *(const floatx4*)(wf + geb + 4);
                u16x8 tb = { f2bf(b0.x), f2bf(b0.y), f2bf(b0.z), f2bf(b0.w),
                             f2bf(b1.x), f2bf(b1.y), f2bf(b1.z), f2bf(b1.w) };
                *(u16x8*)&lB[eoff] = tb;
            } else {
                *(u16x8*)&lA[eoff] = *(const u16x8*)(xb + gea);
                *(u16x8*)&lB[eoff] = *(const u16x8*)(wb + geb);
            }
        }
        __syncthreads();
#pragma unroll
        for (int kk = 0; kk < 2; ++kk) {
            bf16x8 afrag[4], bfrag[4];
            const int kcol = kk * 32 + (lane >> 4) * 8;
#pragma unroll
            for (int i = 0; i < 4; ++i)
                afrag[i] = *(const bf16x8*)&lA[(wave_m * 64 + i * 16 + (lane & 15)) * 64 + kcol];
#pragma unroll
            for (int j = 0; j < 4; ++j)
                bfrag[j] = *(const bf16x8*)&lB[(wave_n * 64 + j * 16 + (lane & 15)) * 64 + kcol];
#pragma unroll
            for (int i = 0; i < 4; ++i)
#pragma unroll
                for (int j = 0; j < 4; ++j)
                    acc[i][j] = __builtin_amdgcn_mfma_f32_16x16x32_bf16(
                        afrag[i], bfrag[j], acc[i][j], 0, 0, 0);
        }
        __syncthreads();
    }

    // -------- epilogue --------
    const u16*    hb  = (const u16*)hv_;   const float*   hf  = (const float*)hv_;
    const ushort4* cbb4 = (const ushort4*)cbv;
    const floatx4* cbf4 = (const floatx4*)cbv;
    const u16*   bib = (const u16*)biv;   const float*  bif = (const float*)biv;
    const u16*   cwb = (const u16*)cwv;   const float*  cwf = (const float*)cwv;
    const u16*   cbsb = (const u16*)cbsv; const float*  cbsf = (const float*)cbsv;

    u16*   outb = (u16*)outv;   float* outf = (float*)outv;
    u16*     hnewb = outb + ELEMS_OUT;            float*   hnewf = outf + ELEMS_OUT;
    ushort4* nbb4  = (ushort4*)(outb + ELEMS_OUT + ELEMS_HNEW);
    floatx4* nbf4  = (floatx4*)(outf + ELEMS_OUT + ELEMS_HNEW);

    const int col  = lane & 15;
    const int rgrp = (lane >> 4) * 4;

#pragma unroll
    for (int j = 0; j < 2; ++j) {
        const int d = n0 + wave_n * 32 + j * 16 + col;
        float binx, binz, w0, w1, w2, w3, cbias;
        if (isf32) {
            binx = bif[d]; binz = bif[1024 + d];
            w0 = cwf[d * 4]; w1 = cwf[d * 4 + 1]; w2 = cwf[d * 4 + 2]; w3 = cwf[d * 4 + 3];
            cbias = cbsf[d];
        } else {
            binx = bf2f(bib[d]); binz = bf2f(bib[1024 + d]);
            const ushort4 w4u = *(const ushort4*)&cwb[d * 4];
            w0 = bf2f(w4u.x); w1 = bf2f(w4u.y); w2 = bf2f(w4u.z); w3 = bf2f(w4u.w);
            cbias = bf2f(cbsb[d]);
        }
        // decay[d] = exp(-exp(-(ln10 + d*(ln2000-ln10)/1023)))
        const float lin = 2.302585092994046f + (float)d * (5.298317366548036f / 1023.0f);
        const float dec = __expf(-__expf(-lin));
        const float one_m_dec = 1.f - dec;
#pragma unroll
        for (int i = 0; i < 4; ++i) {
            const int brow = m0 + wave_m * 64 + i * 16 + rgrp;
#pragma unroll
            for (int r = 0; r < 4; ++r) {
                const size_t idx = (size_t)(brow + r) * D_SZ + d;
                const float xin = acc[i][j][r] + binx;
                const float zv  = acc[i][j + 2][r] + binz;
                float c1, c2, c3, hvv;
                if (isf32) {
                    floatx4 cb = cbf4[idx];
                    c1 = cb.y; c2 = cb.z; c3 = cb.w;
                    hvv = hf[idx];
                } else {
                    ushort4 cb = cbb4[idx];
                    c1 = bf2f(cb.y); c2 = bf2f(cb.z); c3 = bf2f(cb.w);
                    hvv = bf2f(hb[idx]);
                }
                float conv = c1 * w0 + c2 * w1 + c3 * w2 + xin * w3 + cbias;
                const float sc = silu_f(conv);
                const float hn = dec * hvv + one_m_dec * sc;
                if (isf32) {
                    hnewf[idx] = hn;
                    floatx4 nb = { c1, c2, c3, xin };
                    nbf4[idx] = nb;
                } else {
                    hnewb[idx] = f2bf(hn);
                    ushort4 nb;
                    nb.x = f2bf(c1); nb.y = f2bf(c2); nb.z = f2bf(c3); nb.w = f2bf(xin);
                    nbb4[idx] = nb;
                }
                g_out[idx] = f2bf(hn * silu_f(zv));
            }
        }
    }
}

// ---------------------------------------------------------------------------
// Kernel 2: out = g @ W_out^T + b_out  (M=8192, N=1024, K=1024), g is bf16 ws
// ---------------------------------------------------------------------------
__global__ __launch_bounds__(256)
void k2_outproj(const u16* __restrict__ g, const void* __restrict__ wov,
                const void* __restrict__ bov, void* __restrict__ outv,
                const int* __restrict__ flagp)
{
    __shared__ u16 lA[128 * 64];
    __shared__ u16 lB[128 * 64];

    const int isf32 = *flagp;
    const u16*  wb = (const u16*)wov;  const float* wf = (const float*)wov;
    const u16*  bb = (const u16*)bov;  const float* bf = (const float*)bov;
    u16* outb = (u16*)outv;            float* outf = (float*)outv;

    const int tid  = threadIdx.x;
    const int lane = tid & 63;
    const int wv   = tid >> 6;
    const int wave_m = wv >> 1, wave_n = wv & 1;
    const int m0 = blockIdx.x * 128;
    const int n0 = blockIdx.y * 128;

    floatx4 acc[4][4];
#pragma unroll
    for (int i = 0; i < 4; ++i)
#pragma unroll
        for (int j = 0; j < 4; ++j) acc[i][j] = (floatx4){0.f, 0.f, 0.f, 0.f};

    for (int kt = 0; kt < 16; ++kt) {
        const int kbase = kt * 64;
#pragma unroll
        for (int c = 0; c < 4; ++c) {
            const int eoff = wv * 2048 + c * 512 + lane * 8;
            const int row  = eoff >> 6;
            const int cole = eoff & 63;
            const size_t gea = (size_t)(m0 + row) * D_SZ + kbase + cole;
            const size_t geb = (size_t)(n0 + row) * D_SZ + kbase + cole;
            *(u16x8*)&lA[eoff] = *(const u16x8*)(g + gea);
            if (isf32) {
                floatx4 b0 = *(const floatx4*)(wf + geb);
                floatx4 b1 = *(const floatx4*)(wf + geb + 4);
                u16x8 tb = { f2bf(b0.x), f2bf(b0.y), f2bf(b0.z), f2bf(b0.w),
                             f2bf(b1.x), f2bf(b1.y), f2bf(b1.z), f2bf(b1.w) };
                *(u16x8*)&lB[eoff] = tb;
            } else {
                *(u16x8*)&lB[eoff] = *(const u16x8*)(wb + geb);
            }
        }
        __syncthreads();
#pragma unroll
        for (int kk = 0; kk < 2; ++kk) {
            bf16x8 afrag[4], bfrag[4];
            const int kcol = kk * 32 + (lane >> 4) * 8;
#pragma unroll
            for (int i = 0; i < 4; ++i)
                afrag[i] = *(const bf16x8*)&lA[(wave_m * 64 + i * 16 + (lane & 15)) * 64 + kcol];
#pragma unroll
            for (int j = 0; j < 4; ++j)
                bfrag[j] = *(const bf16x8*)&lB[(wave_n * 64 + j * 16 + (lane & 15)) * 64 + kcol];
#pragma unroll
            for (int i = 0; i < 4; ++i)
#pragma unroll
                for (int j = 0; j < 4; ++j)
                    acc[i][j] = __builtin_amdgcn_mfma_f32_16x16x32_bf16(
                        afrag[i], bfrag[j], acc[i][j], 0, 0, 0);
        }
        __syncthreads();
    }

    const int col  = lane & 15;
    const int rgrp = (lane >> 4) * 4;
#pragma unroll
    for (int j = 0; j < 4; ++j) {
        const int n = n0 + wave_n * 64 + j * 16 + col;
        const float bias = isf32 ? bf[n] : bf2f(bb[n]);
#pragma unroll
        for (int i = 0; i < 4; ++i) {
            const int brow = m0 + wave_m * 64 + i * 16 + rgrp;
#pragma unroll
            for (int r = 0; r < 4; ++r) {
                const size_t idx = (size_t)(brow + r) * D_SZ + n;
                const float v = acc[i][j][r] + bias;
                if (isf32) outf[idx] = v; else outb[idx] = f2bf(v);
            }
        }
    }
}

extern "C" void kernel_launch(void* const* d_in, const int* in_sizes, int n_in,
                              void* d_out, int out_size, void* d_ws, size_t ws_size,
                              hipStream_t stream) {
    const void* x        = d_in[0];
    const void* h        = d_in[1];
    const void* conv_buf = d_in[2];
    const void* W_in     = d_in[3];
    const void* b_in     = d_in[4];
    const void* conv_w   = d_in[6 - 1]; // d_in[5]
    const void* conv_b   = d_in[6];
    const void* W_out    = d_in[7];
    const void* b_out    = d_in[8];

    int* flag = (int*)d_ws;
    u16* gbuf = (u16*)((char*)d_ws + 256);   // [8192,1024] bf16 scratch

    k_sniff<<<1, 64, 0, stream>>>((const u16*)x, flag);
    k1_inproj_fused<<<dim3(64, 16), 256, 0, stream>>>(
        x, h, conv_buf, W_in, b_in, conv_w, conv_b, d_out, gbuf, flag);
    k2_outproj<<<dim3(64, 8), 256, 0, stream>>>(gbuf, W_out, b_out, d_out, flag);
}